// Round 1
// baseline (998.334 us; speedup 1.0000x reference)
//
#include <hip/hip_runtime.h>
#include <hip/hip_fp16.h>

#define INVS 0.35355339059327373f  // 1/(2*sqrt(2))
#define CCH 28

// 8-coeff 3D Haar butterfly. c[b], b = u*4+v*2+w (u=z,v=y,w=x subband letter).
// o[p*4+q*2+r] = INVS * sum_{uvw} c[uvw] * S[u,p]S[v,q]S[w,r], S=[[1,1],[1,-1]]
__device__ __forceinline__ void haar8(const float c[8], float o[8]) {
    float t00p = c[0] + c[1], t00m = c[0] - c[1];   // t[u][v][r]
    float t01p = c[2] + c[3], t01m = c[2] - c[3];
    float t10p = c[4] + c[5], t10m = c[4] - c[5];
    float t11p = c[6] + c[7], t11m = c[6] - c[7];
    float u00p = t00p + t01p, u00m = t00m + t01m;   // U[u][q][r]
    float u01p = t00p - t01p, u01m = t00m - t01m;
    float u10p = t10p + t11p, u10m = t10m + t11m;
    float u11p = t10p - t11p, u11m = t10m - t11m;
    o[0] = (u00p + u10p) * INVS;  o[1] = (u00m + u10m) * INVS;  // p0 q0 r0/1
    o[2] = (u01p + u11p) * INVS;  o[3] = (u01m + u11m) * INVS;  // p0 q1
    o[4] = (u00p - u10p) * INVS;  o[5] = (u00m - u10m) * INVS;  // p1 q0
    o[6] = (u01p - u11p) * INVS;  o[7] = (u01m - u11m) * INVS;  // p1 q1
}

// IDWT level -> channel-first fp32 output (C, 2D, 2D, 2D).
// One thread per (c, coarse cell), x-fastest: coalesced reads, float2 stores.
template <int LOGD>
__global__ void idwt_cf(const float* __restrict__ approx,
                        const float* __restrict__ details,
                        float* __restrict__ out) {
    constexpr int D  = 1 << LOGD;
    constexpr int D3 = D * D * D;
    int t  = blockIdx.x * blockDim.x + threadIdx.x;
    int xc = t & (D - 1);
    int yc = (t >> LOGD) & (D - 1);
    int zc = (t >> (2 * LOGD)) & (D - 1);
    int c  = t >> (3 * LOGD);
    if (c >= CCH) return;
    int base = c * D3 + ((zc * D + yc) * D + xc);
    float cf[8];
    cf[0] = approx[base];
#pragma unroll
    for (int j = 0; j < 7; ++j) cf[j + 1] = details[j * (CCH * D3) + base];
    float o[8];
    haar8(cf, o);
    constexpr int D2 = 2 * D;
    float2* outv = (float2*)out;
    // float2 index: ((c*D2 + zf)*D2 + yf)*D + xc
    long ob = (((long)c * D2 + 2 * zc) * D2 + 2 * yc) * D + xc;
    outv[ob]                    = make_float2(o[0], o[1]);  // p0 q0
    outv[ob + D]                = make_float2(o[2], o[3]);  // p0 q1
    outv[ob + (long)D2 * D]     = make_float2(o[4], o[5]);  // p1 q0
    outv[ob + (long)D2 * D + D] = make_float2(o[6], o[7]);  // p1 q1
}

// Final IDWT level: (C,64^3) fp32 -> (128,128,128,C) fp16 channel-last.
// Block = 448 threads = 16 cells x 28 channels, c fastest (near-contiguous
// channel-last stores; coeff lines reused across the block's 16 cells via L1).
__global__ void idwt_last(const float* __restrict__ vol1,
                          const float* __restrict__ details,
                          __half* __restrict__ out) {
    constexpr int D = 64, D3 = D * D * D;
    int c     = threadIdx.x % CCH;
    int lcell = threadIdx.x / CCH;
    int cell  = blockIdx.x * 16 + lcell;
    int xc = cell & 63, yc = (cell >> 6) & 63, zc = cell >> 12;
    int base = c * D3 + cell;
    float cf[8];
    cf[0] = vol1[base];
#pragma unroll
    for (int j = 0; j < 7; ++j) cf[j + 1] = details[j * (CCH * D3) + base];
    float o[8];
    haar8(cf, o);
    // out idx = ((zf*128 + yf)*128 + xf)*28 + c
    const int SX = CCH, SY = 128 * CCH, SZ = 128 * 128 * CCH;
    int ob = (((2 * zc) * 128 + 2 * yc) * 128 + 2 * xc) * CCH + c;
    out[ob]                = __float2half(o[0]);
    out[ob + SX]           = __float2half(o[1]);
    out[ob + SY]           = __float2half(o[2]);
    out[ob + SY + SX]      = __float2half(o[3]);
    out[ob + SZ]           = __float2half(o[4]);
    out[ob + SZ + SX]      = __float2half(o[5]);
    out[ob + SZ + SY]      = __float2half(o[6]);
    out[ob + SZ + SY + SX] = __float2half(o[7]);
}

// Trilinear query: vol (128,128,128,28) fp16 channel-last, out (N,28) fp32.
__global__ void __launch_bounds__(256) query_k(const float* __restrict__ xyz,
                                               const __half* __restrict__ vol,
                                               float* __restrict__ out, int N) {
    int q = blockIdx.x * 256 + threadIdx.x;
    if (q >= N) return;
    const float R1 = 63.5f;             // 0.5*(R-1)
    const float IB = 1.0f / 1.5f;       // 1/bound
    float px = (xyz[3 * q + 0] * IB + 1.0f) * R1;
    float py = (xyz[3 * q + 1] * IB + 1.0f) * R1;
    float pz = (xyz[3 * q + 2] * IB + 1.0f) * R1;
    float flx = floorf(px), fly = floorf(py), flz = floorf(pz);
    int ix0 = (int)flx, iy0 = (int)fly, iz0 = (int)flz;
    float fx = px - flx, fy = py - fly, fz = pz - flz;
    float acc[CCH];
#pragma unroll
    for (int i = 0; i < CCH; ++i) acc[i] = 0.0f;
#pragma unroll
    for (int dz = 0; dz < 2; ++dz) {
        int iz = iz0 + dz;
        bool vz = (iz >= 0) & (iz < 128);
        float wz = dz ? fz : 1.0f - fz;
        int izc = min(max(iz, 0), 127);
#pragma unroll
        for (int dy = 0; dy < 2; ++dy) {
            int iy = iy0 + dy;
            bool vy = (iy >= 0) & (iy < 128);
            float wy = dy ? fy : 1.0f - fy;
            int iyc = min(max(iy, 0), 127);
#pragma unroll
            for (int dx = 0; dx < 2; ++dx) {
                int ix = ix0 + dx;
                bool vx = (ix >= 0) & (ix < 128);
                float wx = dx ? fx : 1.0f - fx;
                int ixc = min(max(ix, 0), 127);
                float w = (vx & vy & vz) ? (wx * wy * wz) : 0.0f;
                int base = ((izc * 128 + iyc) * 128 + ixc) * CCH;
                const uint2* p = (const uint2*)(vol + base);  // 56B-aligned -> 8B ok
#pragma unroll
                for (int j = 0; j < 7; ++j) {
                    uint2 u = p[j];
                    union { unsigned int ui; __half2 h; } a, b;
                    a.ui = u.x; b.ui = u.y;
                    float2 f0 = __half22float2(a.h);
                    float2 f1 = __half22float2(b.h);
                    acc[4 * j + 0] += w * f0.x;
                    acc[4 * j + 1] += w * f0.y;
                    acc[4 * j + 2] += w * f1.x;
                    acc[4 * j + 3] += w * f1.y;
                }
            }
        }
    }
    float4* o4 = (float4*)(out + (long)q * CCH);  // 112B rows: 16B aligned
#pragma unroll
    for (int j = 0; j < 7; ++j)
        o4[j] = make_float4(acc[4 * j], acc[4 * j + 1], acc[4 * j + 2], acc[4 * j + 3]);
}

extern "C" void kernel_launch(void* const* d_in, const int* in_sizes, int n_in,
                              void* d_out, int out_size, void* d_ws, size_t ws_size,
                              hipStream_t stream) {
    const float* approx = (const float*)d_in[0];   // (28,16,16,16)
    const float* det0   = (const float*)d_in[1];   // (7,28,16,16,16)
    const float* det1   = (const float*)d_in[2];   // (7,28,32,32,32)
    const float* det2   = (const float*)d_in[3];   // (7,28,64,64,64)
    const float* xyz    = (const float*)d_in[4];   // (N,3)
    int N = in_sizes[4] / 3;

    char* ws = (char*)d_ws;
    // vol0: 28*32^3 fp32 = 3,670,016 B ; vol1: 28*64^3 fp32 = 29,360,128 B ;
    // vol2: 128^3*28 fp16 = 117,440,512 B ; total ~150.5 MB of workspace.
    float*  vol0 = (float*)ws;
    float*  vol1 = (float*)(ws + 3670016);
    __half* vol2 = (__half*)(ws + 3670016 + 29360128);

    idwt_cf<4><<<448, 256, 0, stream>>>(approx, det0, vol0);    // 28*16^3 threads
    idwt_cf<5><<<3584, 256, 0, stream>>>(vol0, det1, vol1);     // 28*32^3 threads
    idwt_last<<<16384, 448, 0, stream>>>(vol1, det2, vol2);     // 64^3*28 threads
    query_k<<<(N + 255) / 256, 256, 0, stream>>>(xyz, vol2, (float*)d_out, N);
}

// Round 2
// 866.487 us; speedup vs baseline: 1.1522x; 1.1522x over previous
//
#include <hip/hip_runtime.h>
#include <hip/hip_fp16.h>

#define INVS 0.35355339059327373f  // 1/(2*sqrt(2))
#define CCH 28
#define CPAD 32                    // channel-last pad -> 64B voxels, line-aligned
#define XPAD 130                   // LDS xf stride (pad 128->130): phase-2 conflict-free

// 8-coeff 3D Haar butterfly. c[b], b = u*4+v*2+w; o[p*4+q*2+r].
__device__ __forceinline__ void haar8(const float c[8], float o[8]) {
    float t00p = c[0] + c[1], t00m = c[0] - c[1];
    float t01p = c[2] + c[3], t01m = c[2] - c[3];
    float t10p = c[4] + c[5], t10m = c[4] - c[5];
    float t11p = c[6] + c[7], t11m = c[6] - c[7];
    float u00p = t00p + t01p, u00m = t00m + t01m;
    float u01p = t00p - t01p, u01m = t00m - t01m;
    float u10p = t10p + t11p, u10m = t10m + t11m;
    float u11p = t10p - t11p, u11m = t10m - t11m;
    o[0] = (u00p + u10p) * INVS;  o[1] = (u00m + u10m) * INVS;
    o[2] = (u01p + u11p) * INVS;  o[3] = (u01m + u11m) * INVS;
    o[4] = (u00p - u10p) * INVS;  o[5] = (u00m - u10m) * INVS;
    o[6] = (u01p - u11p) * INVS;  o[7] = (u01m - u11m) * INVS;
}

// Levels 0/1: channel-first fp16 output (C, 2D, 2D, 2D). x-fastest threads:
// coalesced reads, coalesced half2 stores.
template <int LOGD, typename TA>
__global__ void idwt_cf_h(const TA* __restrict__ approx,
                          const float* __restrict__ details,
                          __half* __restrict__ out) {
    constexpr int D  = 1 << LOGD;
    constexpr int D3 = D * D * D;
    int t  = blockIdx.x * blockDim.x + threadIdx.x;
    int xc = t & (D - 1);
    int yc = (t >> LOGD) & (D - 1);
    int zc = (t >> (2 * LOGD)) & (D - 1);
    int c  = t >> (3 * LOGD);
    if (c >= CCH) return;
    int base = c * D3 + ((zc * D + yc) * D + xc);
    float cf[8];
    cf[0] = (float)approx[base];
#pragma unroll
    for (int j = 0; j < 7; ++j) cf[j + 1] = details[j * (CCH * D3) + base];
    float o[8];
    haar8(cf, o);
    constexpr int D2 = 2 * D;
    __half2* outv = (__half2*)out;  // half2 = x-pair
    int ob = (((c * D2 + 2 * zc) * D2 + 2 * yc) * D + xc);
    __half2 h01, h23, h45, h67;
    h01.x = __float2half(o[0]); h01.y = __float2half(o[1]);
    h23.x = __float2half(o[2]); h23.y = __float2half(o[3]);
    h45.x = __float2half(o[4]); h45.y = __float2half(o[5]);
    h67.x = __float2half(o[6]); h67.y = __float2half(o[7]);
    outv[ob]              = h01;  // zf=2zc,   yf=2yc
    outv[ob + D]          = h23;  // zf=2zc,   yf=2yc+1
    outv[ob + D2 * D]     = h45;  // zf=2zc+1, yf=2yc
    outv[ob + D2 * D + D] = h67;  // zf=2zc+1, yf=2yc+1
}

// Level 2: (28,64^3) fp16 channel-first -> (128,128,128,32) fp16 channel-last.
// One block per coarse (zc,yc) row: 28ch x 64 cells. Phase 1: coalesced reads
// (lanes = xc), haar, scatter to LDS [plane][c][xf] (xf-stride 130: writes are
// 2-way = free, reads conflict-free). Phase 2: contiguous uint4 global stores.
__global__ void __launch_bounds__(256) idwt_last(const __half* __restrict__ vol1,
                                                 const float* __restrict__ details,
                                                 __half* __restrict__ out) {
    constexpr int D3 = 64 * 64 * 64;
    __shared__ unsigned short lds[4 * CPAD * XPAD];  // 33,280 B
    int zc = blockIdx.x >> 6, yc = blockIdx.x & 63;
    int rowc = (zc * 64 + yc) * 64;
#pragma unroll
    for (int it = 0; it < 7; ++it) {           // 7*256 = 28ch * 64cells
        int item = it * 256 + threadIdx.x;
        int c = item >> 6, xc = item & 63;     // wave: fixed c, xc 0..63
        int base = c * D3 + rowc + xc;
        float cf[8];
        cf[0] = (float)vol1[base];
#pragma unroll
        for (int j = 0; j < 7; ++j) cf[j + 1] = details[j * (CCH * D3) + base];
        float o[8];
        haar8(cf, o);
#pragma unroll
        for (int k = 0; k < 8; ++k) {          // k = p*4+q*2+r
            int p2q = k >> 1, r = k & 1;
            int xf = 2 * xc + r;
            lds[(p2q * CPAD + c) * XPAD + xf] = __half_as_ushort(__float2half(o[k]));
        }
    }
    __syncthreads();
    // 4 output rows of 128 voxels x 32 halves = 2048 uint4 chunks.
#pragma unroll
    for (int t2i = 0; t2i < 8; ++t2i) {
        int t2 = t2i * 256 + threadIdx.x;
        int plane = t2 >> 9, rem = t2 & 511, v = rem >> 2, k = rem & 3;
        int p = plane >> 1, q = plane & 1;
        unsigned int h[8];
#pragma unroll
        for (int j = 0; j < 8; ++j)
            h[j] = lds[(plane * CPAD + 8 * k + j) * XPAD + v];
        uint4 r4;
        r4.x = h[0] | (h[1] << 16);
        r4.y = h[2] | (h[3] << 16);
        r4.z = h[4] | (h[5] << 16);
        r4.w = h[6] | (h[7] << 16);
        long orow = (((long)(2 * zc + p) * 128 + (2 * yc + q)) * 128) * CPAD;
        ((uint4*)(out + orow))[rem] = r4;      // contiguous per wave
    }
}

// Trilinear query: vol (128,128,128,32) fp16 channel-last padded, out (N,28) fp32.
// Each corner = one aligned 64B line (4x dwordx4).
__global__ void __launch_bounds__(256) query_k(const float* __restrict__ xyz,
                                               const __half* __restrict__ vol,
                                               float* __restrict__ out, int N) {
    int q = blockIdx.x * 256 + threadIdx.x;
    if (q >= N) return;
    const float R1 = 63.5f;        // 0.5*(R-1)
    const float IB = 1.0f / 1.5f;  // 1/bound
    float px = (xyz[3 * q + 0] * IB + 1.0f) * R1;
    float py = (xyz[3 * q + 1] * IB + 1.0f) * R1;
    float pz = (xyz[3 * q + 2] * IB + 1.0f) * R1;
    float flx = floorf(px), fly = floorf(py), flz = floorf(pz);
    int ix0 = (int)flx, iy0 = (int)fly, iz0 = (int)flz;
    float fx = px - flx, fy = py - fly, fz = pz - flz;
    float acc[CPAD];
#pragma unroll
    for (int i = 0; i < CPAD; ++i) acc[i] = 0.0f;
#pragma unroll
    for (int dz = 0; dz < 2; ++dz) {
        int iz = iz0 + dz;
        bool vz = (iz >= 0) & (iz < 128);
        float wz = dz ? fz : 1.0f - fz;
        int izc = min(max(iz, 0), 127);
#pragma unroll
        for (int dy = 0; dy < 2; ++dy) {
            int iy = iy0 + dy;
            bool vy = (iy >= 0) & (iy < 128);
            float wy = dy ? fy : 1.0f - fy;
            int iyc = min(max(iy, 0), 127);
#pragma unroll
            for (int dx = 0; dx < 2; ++dx) {
                int ix = ix0 + dx;
                bool vx = (ix >= 0) & (ix < 128);
                float wx = dx ? fx : 1.0f - fx;
                int ixc = min(max(ix, 0), 127);
                float w = (vx & vy & vz) ? (wx * wy * wz) : 0.0f;
                const uint4* p4 =
                    (const uint4*)(vol + (long)((izc * 128 + iyc) * 128 + ixc) * CPAD);
#pragma unroll
                for (int j = 0; j < 4; ++j) {   // 64B-aligned line
                    uint4 u = p4[j];
                    union { unsigned int ui; __half2 h; } a, b, c2, d2;
                    a.ui = u.x; b.ui = u.y; c2.ui = u.z; d2.ui = u.w;
                    float2 f0 = __half22float2(a.h);
                    float2 f1 = __half22float2(b.h);
                    float2 f2 = __half22float2(c2.h);
                    float2 f3 = __half22float2(d2.h);
                    acc[8 * j + 0] += w * f0.x;
                    acc[8 * j + 1] += w * f0.y;
                    acc[8 * j + 2] += w * f1.x;
                    acc[8 * j + 3] += w * f1.y;
                    acc[8 * j + 4] += w * f2.x;
                    acc[8 * j + 5] += w * f2.y;
                    acc[8 * j + 6] += w * f3.x;
                    acc[8 * j + 7] += w * f3.y;
                }
            }
        }
    }
    float4* o4 = (float4*)(out + (long)q * CCH);  // 112B rows, 16B aligned
#pragma unroll
    for (int j = 0; j < 7; ++j)
        o4[j] = make_float4(acc[4 * j], acc[4 * j + 1], acc[4 * j + 2], acc[4 * j + 3]);
}

extern "C" void kernel_launch(void* const* d_in, const int* in_sizes, int n_in,
                              void* d_out, int out_size, void* d_ws, size_t ws_size,
                              hipStream_t stream) {
    const float* approx = (const float*)d_in[0];   // (28,16,16,16)
    const float* det0   = (const float*)d_in[1];   // (7,28,16,16,16)
    const float* det1   = (const float*)d_in[2];   // (7,28,32,32,32)
    const float* det2   = (const float*)d_in[3];   // (7,28,64,64,64)
    const float* xyz    = (const float*)d_in[4];   // (N,3)
    int N = in_sizes[4] / 3;

    char* ws = (char*)d_ws;
    // vol0: 28*32^3 fp16 = 1,835,008 B
    // vol1: 28*64^3 fp16 = 14,680,064 B
    // vol2: 128^3*32 fp16 = 134,217,728 B   (total 150,732,800 B)
    __half* vol0 = (__half*)ws;
    __half* vol1 = (__half*)(ws + 1835008);
    __half* vol2 = (__half*)(ws + 1835008 + 14680064);

    idwt_cf_h<4, float><<<448, 256, 0, stream>>>(approx, det0, vol0);
    idwt_cf_h<5, __half><<<3584, 256, 0, stream>>>(vol0, det1, vol1);
    idwt_last<<<4096, 256, 0, stream>>>(vol1, det2, vol2);
    query_k<<<(N + 255) / 256, 256, 0, stream>>>(xyz, vol2, (float*)d_out, N);
}

// Round 3
// 655.256 us; speedup vs baseline: 1.5236x; 1.3224x over previous
//
#include <hip/hip_runtime.h>
#include <hip/hip_fp16.h>

#define INVS 0.35355339059327373f  // 1/(2*sqrt(2))
#define CCH 28
#define RS 129                     // query LDS row stride (dwords): odd -> bank spread

// 8-coeff 3D Haar butterfly. c[b], b = u*4+v*2+w; o[p*4+q*2+r].
__device__ __forceinline__ void haar8(const float c[8], float o[8]) {
    float t00p = c[0] + c[1], t00m = c[0] - c[1];
    float t01p = c[2] + c[3], t01m = c[2] - c[3];
    float t10p = c[4] + c[5], t10m = c[4] - c[5];
    float t11p = c[6] + c[7], t11m = c[6] - c[7];
    float u00p = t00p + t01p, u00m = t00m + t01m;
    float u01p = t00p - t01p, u01m = t00m - t01m;
    float u10p = t10p + t11p, u10m = t10m + t11m;
    float u11p = t10p - t11p, u11m = t10m - t11m;
    o[0] = (u00p + u10p) * INVS;  o[1] = (u00m + u10m) * INVS;
    o[2] = (u01p + u11p) * INVS;  o[3] = (u01m + u11m) * INVS;
    o[4] = (u00p - u10p) * INVS;  o[5] = (u00m - u10m) * INVS;
    o[6] = (u01p - u11p) * INVS;  o[7] = (u01m - u11m) * INVS;
}

// Pixel coords with NO fma contraction (__f*_rn): bit-identical across kernels,
// so hist_k and scatter_k agree on every query's cell.
__device__ __forceinline__ float3 pixcoord(float x, float y, float z) {
    const float R1 = 63.5f, IB = 1.0f / 1.5f;
    float3 p;
    p.x = __fmul_rn(__fadd_rn(__fmul_rn(x, IB), 1.0f), R1);
    p.y = __fmul_rn(__fadd_rn(__fmul_rn(y, IB), 1.0f), R1);
    p.z = __fmul_rn(__fadd_rn(__fmul_rn(z, IB), 1.0f), R1);
    return p;
}
__device__ __forceinline__ int cell_of(float3 p) {
    int cx = min(max((int)floorf(p.x), 0), 127) >> 3;
    int cy = min(max((int)floorf(p.y), 0), 127) >> 3;
    int cz = min(max((int)floorf(p.z), 0), 127) >> 3;
    return (cz * 16 + cy) * 16 + cx;
}

// Levels 0/1: channel-first fp16 output (C, 2D, 2D, 2D). x-fastest threads.
template <int LOGD, typename TA>
__global__ void idwt_cf_h(const TA* __restrict__ approx,
                          const float* __restrict__ details,
                          __half* __restrict__ out) {
    constexpr int D  = 1 << LOGD;
    constexpr int D3 = D * D * D;
    int t  = blockIdx.x * blockDim.x + threadIdx.x;
    int xc = t & (D - 1);
    int yc = (t >> LOGD) & (D - 1);
    int zc = (t >> (2 * LOGD)) & (D - 1);
    int c  = t >> (3 * LOGD);
    if (c >= CCH) return;
    int base = c * D3 + ((zc * D + yc) * D + xc);
    float cf[8];
    cf[0] = (float)approx[base];
#pragma unroll
    for (int j = 0; j < 7; ++j) cf[j + 1] = details[j * (CCH * D3) + base];
    float o[8];
    haar8(cf, o);
    constexpr int D2 = 2 * D;
    __half2* outv = (__half2*)out;  // half2 = x-pair
    int ob = (((c * D2 + 2 * zc) * D2 + 2 * yc) * D + xc);
    __half2 h01, h23, h45, h67;
    h01.x = __float2half(o[0]); h01.y = __float2half(o[1]);
    h23.x = __float2half(o[2]); h23.y = __float2half(o[3]);
    h45.x = __float2half(o[4]); h45.y = __float2half(o[5]);
    h67.x = __float2half(o[6]); h67.y = __float2half(o[7]);
    outv[ob]              = h01;
    outv[ob + D]          = h23;
    outv[ob + D2 * D]     = h45;
    outv[ob + D2 * D + D] = h67;
}

// Level 2: (28,64^3) fp16 ch-first -> (128,128,128,28) fp16 channel-last.
__global__ void __launch_bounds__(256) idwt_last(const __half* __restrict__ vol1,
                                                 const float* __restrict__ details,
                                                 __half* __restrict__ out) {
    constexpr int D3 = 64 * 64 * 64;
    __shared__ unsigned short lds[4 * CCH * 130];  // 29,120 B
    int zc = blockIdx.x >> 6, yc = blockIdx.x & 63;
    int rowc = (zc * 64 + yc) * 64;
#pragma unroll 1
    for (int it = 0; it < 7; ++it) {           // 7*256 = 28ch * 64cells
        int item = it * 256 + threadIdx.x;
        int c = item >> 6, xc = item & 63;     // wave: fixed c, xc 0..63
        int base = c * D3 + rowc + xc;
        float cf[8];
        cf[0] = (float)vol1[base];
#pragma unroll
        for (int j = 0; j < 7; ++j) cf[j + 1] = details[j * (CCH * D3) + base];
        float o[8];
        haar8(cf, o);
#pragma unroll
        for (int k = 0; k < 8; ++k) {          // k = p*4+q*2+r
            int p2q = k >> 1, r = k & 1;
            lds[(p2q * CCH + c) * 130 + 2 * xc + r] = __half_as_ushort(__float2half(o[k]));
        }
    }
    __syncthreads();
    // 4 fine rows x (128 vox * 28 ch = 3584 halves = 448 uint4) = 1792 chunks.
#pragma unroll 1
    for (int it = 0; it < 7; ++it) {
        int t2 = it * 256 + threadIdx.x;       // 0..1791
        int plane = t2 / 448;
        int rem = t2 - plane * 448;
        int p = plane >> 1, q = plane & 1;
        unsigned int h[8];
#pragma unroll
        for (int j = 0; j < 8; ++j) {
            int f = rem * 8 + j;
            int vox = f / 28;
            int ch = f - 28 * vox;
            h[j] = lds[(plane * CCH + ch) * 130 + vox];
        }
        uint4 r4;
        r4.x = h[0] | (h[1] << 16);
        r4.y = h[2] | (h[3] << 16);
        r4.z = h[4] | (h[5] << 16);
        r4.w = h[6] | (h[7] << 16);
        long orow = ((long)(2 * zc + p) * 128 + (2 * yc + q)) * (128 * CCH);
        ((uint4*)(out + orow))[rem] = r4;      // contiguous per wave
    }
}

__global__ void hist_k(const float* __restrict__ xyz, int* __restrict__ hist, int N) {
    int i = blockIdx.x * 256 + threadIdx.x;
    if (i >= N) return;
    float3 p = pixcoord(xyz[3 * i], xyz[3 * i + 1], xyz[3 * i + 2]);
    atomicAdd(&hist[cell_of(p)], 1);
}

__global__ void __launch_bounds__(256) scan_k(const int* __restrict__ hist,
                                              int* __restrict__ off,
                                              int* __restrict__ cursor) {
    __shared__ int part[256];
    int t = threadIdx.x;
    int loc[16], s = 0;
#pragma unroll
    for (int i = 0; i < 16; ++i) { loc[i] = s; s += hist[t * 16 + i]; }
    part[t] = s;
    __syncthreads();
    for (int d = 1; d < 256; d <<= 1) {        // Hillis-Steele inclusive
        int v = (t >= d) ? part[t - d] : 0;
        __syncthreads();
        part[t] += v;
        __syncthreads();
    }
    int excl = part[t] - s;
#pragma unroll
    for (int i = 0; i < 16; ++i) {
        int o = excl + loc[i];
        off[t * 16 + i] = o;
        cursor[t * 16 + i] = o;
    }
    if (t == 255) off[4096] = part[255];
}

__global__ void scatter_k(const float* __restrict__ xyz, int* __restrict__ cursor,
                          float4* __restrict__ recs, int N) {
    int i = blockIdx.x * 256 + threadIdx.x;
    if (i >= N) return;
    float3 p = pixcoord(xyz[3 * i], xyz[3 * i + 1], xyz[3 * i + 2]);
    int cell = cell_of(p);
    int pos = atomicAdd(&cursor[cell], 1);
    recs[pos] = make_float4(__int_as_float(i), p.x, p.y, p.z);
}

// One block per 8^3 cell: stage 9^3 halo region in LDS, serve queries from LDS.
__global__ void __launch_bounds__(256) query_cell(const float4* __restrict__ recs,
                                                  const int* __restrict__ off,
                                                  const __half* __restrict__ vol,
                                                  float* __restrict__ out) {
    __shared__ unsigned int lds[81 * RS];      // 41,796 B
    int cell = blockIdx.x;
    int cx = cell & 15, cy = (cell >> 4) & 15, cz = cell >> 8;
    const unsigned int* vd = (const unsigned int*)vol;
    const long VOLDW = 128L * 128 * 128 * 14;  // volume in dwords
    // Region: 81 rows (lz,ly) x 9 voxels x 14 dwords = 126 dwords, contiguous.
    for (int d = threadIdx.x; d < 81 * 128; d += 256) {
        int row = d >> 7, k = d & 127;
        if (k >= 126) continue;
        int lz = row / 9, ly = row - 9 * lz;
        int gz = min(8 * cz + lz, 127), gy = min(8 * cy + ly, 127);
        long g = ((long)(gz * 128 + gy) * 128 + 8 * cx) * 14 + k;
        g = min(g, VOLDW - 1);                 // x-overrun at cx=15: finite junk, w=0
        lds[row * RS + k] = vd[g];
    }
    __syncthreads();
    int i1 = off[cell + 1];
    for (int i = off[cell] + (int)threadIdx.x; i < i1; i += 256) {
        float4 r = recs[i];
        int q = __float_as_int(r.x);
        float px = r.y, py = r.z, pz = r.w;
        float flx = floorf(px), fly = floorf(py), flz = floorf(pz);
        int ix0 = (int)flx, iy0 = (int)fly, iz0 = (int)flz;
        float fx = px - flx, fy = py - fly, fz = pz - flz;
        float acc[CCH];
#pragma unroll
        for (int k = 0; k < CCH; ++k) acc[k] = 0.0f;
#pragma unroll
        for (int dz = 0; dz < 2; ++dz) {
            int iz = iz0 + dz;
            bool vz = (iz >= 0) & (iz < 128);
            float wz = dz ? fz : 1.0f - fz;
            int lzc = min(max(iz, 0), 127) - 8 * cz;
#pragma unroll
            for (int dy = 0; dy < 2; ++dy) {
                int iy = iy0 + dy;
                bool vy = (iy >= 0) & (iy < 128);
                float wy = dy ? fy : 1.0f - fy;
                int lyc = min(max(iy, 0), 127) - 8 * cy;
#pragma unroll
                for (int dx = 0; dx < 2; ++dx) {
                    int ix = ix0 + dx;
                    bool vx = (ix >= 0) & (ix < 128);
                    float wx = dx ? fx : 1.0f - fx;
                    int lxc = min(max(ix, 0), 127) - 8 * cx;
                    float w = (vx & vy & vz) ? (wx * wy * wz) : 0.0f;
                    const unsigned int* pr = &lds[(lzc * 9 + lyc) * RS + 14 * lxc];
#pragma unroll
                    for (int j = 0; j < 7; ++j) {
                        unsigned int u0 = pr[2 * j], u1 = pr[2 * j + 1];
                        float2 f0 = __half22float2(*(__half2*)&u0);
                        float2 f1 = __half22float2(*(__half2*)&u1);
                        acc[4 * j + 0] += w * f0.x;
                        acc[4 * j + 1] += w * f0.y;
                        acc[4 * j + 2] += w * f1.x;
                        acc[4 * j + 3] += w * f1.y;
                    }
                }
            }
        }
        float4* o4 = (float4*)(out + (long)q * CCH);  // 112B rows, 16B aligned
#pragma unroll
        for (int j = 0; j < 7; ++j)
            o4[j] = make_float4(acc[4 * j], acc[4 * j + 1], acc[4 * j + 2], acc[4 * j + 3]);
    }
}

extern "C" void kernel_launch(void* const* d_in, const int* in_sizes, int n_in,
                              void* d_out, int out_size, void* d_ws, size_t ws_size,
                              hipStream_t stream) {
    const float* approx = (const float*)d_in[0];   // (28,16,16,16)
    const float* det0   = (const float*)d_in[1];   // (7,28,16,16,16)
    const float* det1   = (const float*)d_in[2];   // (7,28,32,32,32)
    const float* det2   = (const float*)d_in[3];   // (7,28,64,64,64)
    const float* xyz    = (const float*)d_in[4];   // (N,3)
    int N = in_sizes[4] / 3;

    char* ws = (char*)d_ws;
    // vol0  @0          : 1,835,008   (28*32^3 fp16)
    // vol1  @1,835,008  : 14,680,064  (28*64^3 fp16)
    // vol2  @16,515,072 : 117,440,512 (128^3*28 fp16, channel-last)
    // hist  @133,955,584: 16,384
    // off   @133,971,968: 16,388 (pad to 16,400)
    // cursor@133,988,368: 16,384
    // recs  @134,004,752: N*16  -> total 150,004,752 B (< proven 150.73 MB)
    __half* vol0 = (__half*)ws;
    __half* vol1 = (__half*)(ws + 1835008);
    __half* vol2 = (__half*)(ws + 16515072);
    int*    hist = (int*)(ws + 133955584);
    int*    off  = (int*)(ws + 133971968);
    int*    curs = (int*)(ws + 133988368);
    float4* recs = (float4*)(ws + 134004752);

    hipMemsetAsync(hist, 0, 4096 * sizeof(int), stream);
    idwt_cf_h<4, float><<<448, 256, 0, stream>>>(approx, det0, vol0);
    idwt_cf_h<5, __half><<<3584, 256, 0, stream>>>(vol0, det1, vol1);
    idwt_last<<<4096, 256, 0, stream>>>(vol1, det2, vol2);
    int nb = (N + 255) / 256;
    hist_k<<<nb, 256, 0, stream>>>(xyz, hist, N);
    scan_k<<<1, 256, 0, stream>>>(hist, off, curs);
    scatter_k<<<nb, 256, 0, stream>>>(xyz, curs, recs, N);
    query_cell<<<4096, 256, 0, stream>>>(recs, off, vol2, (float*)d_out);
}